// Round 20
// baseline (99.891 us; speedup 1.0000x reference)
//
#include <hip/hip_runtime.h>
#include <math.h>

#define NPTS  16384
#define G     32              // grid cells per axis
#define NC    (G * G * G)     // 32768 cells per set
#define CW    0.25f           // cell width: domain [-4,4]
#define ICW   4.0f            // 1/CW
#define TOTP  65536           // 4 sets x 16384 points
#define TOTQ  32768           // mean denominator: B*N per direction
#define CAP   64              // bucket capacity (cell mean ~17, 11 sigma margin)

// set id: cloud*2 + batch. query set z (0..3) -> ref set z^2 (other cloud, same batch)

__device__ __forceinline__ int cellof(float x) {
    int c = (int)floorf((x + 4.0f) * ICW);
    return min(max(c, 0), G - 1);
}

// zero cnt (131072 ints) + tailcnt (contiguous after cnt)
__global__ __launch_bounds__(256) void zero_kernel(int* __restrict__ cnt) {
    int gid = blockIdx.x * 256 + threadIdx.x;     // 0..32767
    ((int4*)cnt)[gid] = make_int4(0, 0, 0, 0);
    if (gid == 0) cnt[NC * 4] = 0;                // tailcnt
}

// count-and-place: one pass builds the cell buckets directly (no scan/scatter)
__global__ __launch_bounds__(256) void build_kernel(const float* __restrict__ pred,
                                                    const float* __restrict__ target,
                                                    float4* __restrict__ pts,
                                                    float4* __restrict__ bucket,
                                                    int* __restrict__ cnt) {
    int t = blockIdx.x * 256 + threadIdx.x;      // 0..65535
    int cloud = t >> 15, w = t & 32767, b = w >> 14, i = w & 16383;
    const float* src = cloud ? target : pred;
    float x = src[(b * NPTS + i) * 3 + 0];
    float y = src[(b * NPTS + i) * 3 + 1];
    float z = src[(b * NPTS + i) * 3 + 2];
    int set = cloud * 2 + b;
    int c = (cellof(z) * G + cellof(y)) * G + cellof(x);
    int u = (set << 14) + i;
    float4 p = make_float4(x, y, z, 0.f);
    pts[u] = p;                                   // linear query array
    int cellIdx = (set << 15) + c;
    int slot = atomicAdd(&cnt[cellIdx], 1);
    if (slot < CAP) bucket[((size_t)cellIdx << 6) + slot] = p;
}

#define EVAL(p) { float dx = q.x - (p).x, dy = q.y - (p).y, dz2 = q.z - (p).z; \
    md2 = fminf(md2, fmaf(dx, dx, fmaf(dy, dy, dz2 * dz2))); }

// Bulk pass: 8 lanes per query, k=1 box (27 cells), counts hoisted.
__global__ __launch_bounds__(256) void nnA_kernel(const float4* __restrict__ pts,
                                                  const float4* __restrict__ bucket,
                                                  const int* __restrict__ cnt,
                                                  float* __restrict__ dout,
                                                  int* __restrict__ tailcnt,
                                                  int* __restrict__ taillist) {
    const int gthr = blockIdx.x * 256 + threadIdx.x;  // 0..524287
    const int u = gthr >> 3;                          // query id: (set<<14)+i
    const int l8 = gthr & 7;
    const int z = u >> 14;
    float4 q = pts[u];
    const int rs = z ^ 2;
    const int* __restrict__ rcnt = cnt + (rs << 15);
    const float4* __restrict__ rb = bucket + (((size_t)rs << 15) << 6);

    const int cx = cellof(q.x), cy = cellof(q.y), cz = cellof(q.z);

    int cn[27];
    #pragma unroll
    for (int i = 0; i < 27; ++i) {
        const int zz = cz + i / 9 - 1;
        const int yy = cy + (i / 3) % 3 - 1;
        const int xx = cx + i % 3 - 1;
        const bool ok = ((unsigned)zz < G) && ((unsigned)yy < G) && ((unsigned)xx < G);
        cn[i] = ok ? min(rcnt[(zz * G + yy) * G + xx], CAP) : 0;
    }

    float md2 = __builtin_inff();
    #pragma unroll
    for (int i = 0; i < 27; ++i) {
        const int zz = cz + i / 9 - 1;
        const int yy = cy + (i / 3) % 3 - 1;
        const int xx = cx + i % 3 - 1;
        const float4* cb = rb + ((size_t)((zz * G + yy) * G + xx) << 6);
        for (int j = l8; j < cn[i]; j += 8) EVAL(cb[j])
    }

    md2 = fminf(md2, __shfl_xor(md2, 1));
    md2 = fminf(md2, __shfl_xor(md2, 2));
    md2 = fminf(md2, __shfl_xor(md2, 4));

    if (l8 == 0) {
        float g = __builtin_inff();
        if (cx - 1 > 0)     g = fminf(g, q.x - ((cx - 1) * CW - 4.0f));
        if (cx + 1 < G - 1) g = fminf(g, ((cx + 2) * CW - 4.0f) - q.x);
        if (cy - 1 > 0)     g = fminf(g, q.y - ((cy - 1) * CW - 4.0f));
        if (cy + 1 < G - 1) g = fminf(g, ((cy + 2) * CW - 4.0f) - q.y);
        if (cz - 1 > 0)     g = fminf(g, q.z - ((cz - 1) * CW - 4.0f));
        if (cz + 1 < G - 1) g = fminf(g, ((cz + 2) * CW - 4.0f) - q.z);
        if (md2 <= g * g) {
            dout[u] = sqrtf(md2);
        } else {
            int idx = atomicAdd(tailcnt, 1);
            taillist[idx] = u;        // dout[u] written by tail kernel
        }
    }
}

// Tail: ONE WAVE per query; shell k enumerated per-cell, lanes take cells.
// Shell decomposition: 2 z-faces (W*W), 2 y-faces (Wm*W), 2 x-faces (Wm*Wm).
__global__ __launch_bounds__(256) void tail_kernel(const float4* __restrict__ pts,
                                                   const float4* __restrict__ bucket,
                                                   const int* __restrict__ cnt,
                                                   const int* __restrict__ tailcnt,
                                                   const int* __restrict__ taillist,
                                                   float* __restrict__ dout) {
    const int tcnt = *tailcnt;
    const int wid = blockIdx.x * 4 + (threadIdx.x >> 6);
    const int ln = threadIdx.x & 63;
    const int nw = gridDim.x * 4;

    for (int t = wid; t < tcnt; t += nw) {
        const int u = taillist[t];
        const int z = u >> 14;
        float4 q = pts[u];
        const int rs = z ^ 2;
        const int* __restrict__ rcnt = cnt + (rs << 15);
        const float4* __restrict__ rb = bucket + (((size_t)rs << 15) << 6);
        const int cx = cellof(q.x), cy = cellof(q.y), cz = cellof(q.z);

        float md2 = __builtin_inff();

        // k = 0: home cell, lane-strided
        {
            const int ci = (cz * G + cy) * G + cx;
            const int n = min(rcnt[ci], CAP);
            const float4* cb = rb + ((size_t)ci << 6);
            for (int j = ln; j < n; j += 64) EVAL(cb[j])
        }

        for (int k = 1; k < G; ++k) {
            #pragma unroll
            for (int off = 1; off < 64; off <<= 1)
                md2 = fminf(md2, __shfl_xor(md2, off));
            const int km = k - 1;
            float g = __builtin_inff();
            if (cx - km > 0)     g = fminf(g, q.x - ((cx - km) * CW - 4.0f));
            if (cx + km < G - 1) g = fminf(g, ((cx + km + 1) * CW - 4.0f) - q.x);
            if (cy - km > 0)     g = fminf(g, q.y - ((cy - km) * CW - 4.0f));
            if (cy + km < G - 1) g = fminf(g, ((cy + km + 1) * CW - 4.0f) - q.y);
            if (cz - km > 0)     g = fminf(g, q.z - ((cz - km) * CW - 4.0f));
            if (cz + km < G - 1) g = fminf(g, ((cz + km + 1) * CW - 4.0f) - q.z);
            if (md2 <= g * g) break;

            const int W = 2 * k + 1, Wm = 2 * k - 1;
            const int A = 2 * W * W, B = 2 * Wm * W, C = 2 * Wm * Wm;
            const int S = A + B + C;
            for (int m = ln; m < S; m += 64) {
                int zz, yy, xx;
                if (m < A) {                      // z-faces
                    const int f = (m < W * W) ? -k : k;
                    const int r = (m < W * W) ? m : m - W * W;
                    zz = cz + f;
                    yy = cy + r / W - k;
                    xx = cx + r % W - k;
                } else if (m < A + B) {           // y-faces (z interior)
                    const int t2 = m - A;
                    const int f = (t2 < Wm * W) ? -k : k;
                    const int r = (t2 < Wm * W) ? t2 : t2 - Wm * W;
                    zz = cz + r / W - (k - 1);
                    yy = cy + f;
                    xx = cx + r % W - k;
                } else {                          // x-faces (z,y interior)
                    const int t2 = m - A - B;
                    const int f = (t2 < Wm * Wm) ? -k : k;
                    const int r = (t2 < Wm * Wm) ? t2 : t2 - Wm * Wm;
                    zz = cz + r / Wm - (k - 1);
                    yy = cy + r % Wm - (k - 1);
                    xx = cx + f;
                }
                if ((unsigned)zz >= G || (unsigned)yy >= G || (unsigned)xx >= G) continue;
                const int ci = (zz * G + yy) * G + xx;
                const int n = min(rcnt[ci], CAP);
                const float4* cb = rb + ((size_t)ci << 6);
                for (int j = 0; j < n; ++j) EVAL(cb[j])
            }
        }

        #pragma unroll
        for (int off = 1; off < 64; off <<= 1)
            md2 = fminf(md2, __shfl_xor(md2, off));
        if (ln == 0) dout[u] = sqrtf(md2);
    }
}
#undef EVAL

// single-block final reduce: fixed order -> deterministic
__global__ __launch_bounds__(1024) void reduce_kernel(const float* __restrict__ dout,
                                                      float* __restrict__ out) {
    float s = 0.f;
    #pragma unroll
    for (int k = 0; k < 64; ++k)
        s += dout[k * 1024 + threadIdx.x];
    #pragma unroll
    for (int off = 32; off; off >>= 1) s += __shfl_down(s, off);
    __shared__ float wsum[16];
    int lane = threadIdx.x & 63, wv = threadIdx.x >> 6;
    if (lane == 0) wsum[wv] = s;
    __syncthreads();
    if (threadIdx.x == 0) {
        float tt = 0.f;
        #pragma unroll
        for (int i = 0; i < 16; ++i) tt += wsum[i];
        out[0] = tt / (float)TOTQ;
    }
}

extern "C" void kernel_launch(void* const* d_in, const int* in_sizes, int n_in,
                              void* d_out, int out_size, void* d_ws, size_t ws_size,
                              hipStream_t stream) {
    const float* pred   = (const float*)d_in[0];
    const float* target = (const float*)d_in[1];
    char* ws = (char*)d_ws;

    float4* pts      = (float4*)(ws);                                   // 1 MiB
    int*    cnt      = (int*)  (ws + (size_t)1024 * 1024);              // 512 KiB (+tailcnt)
    int*    taillist = (int*)  (ws + (size_t)1664 * 1024);              // 256 KiB
    float*  dout     = (float*)(ws + (size_t)1920 * 1024);              // 256 KiB
    float4* bucket   = (float4*)(ws + (size_t)16 * 1024 * 1024);        // 128 MiB
    int*    tailcnt  = cnt + NC * 4;                                    // after cnt
    float*  out      = (float*)d_out;

    zero_kernel<<<128, 256, 0, stream>>>(cnt);
    build_kernel<<<TOTP / 256, 256, 0, stream>>>(pred, target, pts, bucket, cnt);
    nnA_kernel<<<TOTP * 8 / 256, 256, 0, stream>>>(pts, bucket, cnt, dout, tailcnt, taillist);
    tail_kernel<<<512, 256, 0, stream>>>(pts, bucket, cnt, tailcnt, taillist, dout);
    reduce_kernel<<<1, 1024, 0, stream>>>(dout, out);
}

// Round 21
// 87.763 us; speedup vs baseline: 1.1382x; 1.1382x over previous
//
#include <hip/hip_runtime.h>
#include <math.h>

#define NPTS  16384
#define G     32              // grid cells per axis
#define NC    (G * G * G)     // 32768 cells per set
#define CW    0.25f           // cell width: domain [-4,4]
#define ICW   4.0f            // 1/CW
#define TOTP  65536           // 4 sets x 16384 points
#define TOTQ  32768           // mean denominator: B*N per direction

// set id: cloud*2 + batch. query set z (0..3) -> ref set z^2 (other cloud, same batch)

__device__ __forceinline__ int cellof(float x) {
    int c = (int)floorf((x + 4.0f) * ICW);
    return min(max(c, 0), G - 1);
}

// zero hist (131072 ints) + tailcnt (contiguous after hist)
__global__ __launch_bounds__(256) void zero_kernel(int* __restrict__ hist) {
    int gid = blockIdx.x * 256 + threadIdx.x;     // 0..32767
    ((int4*)hist)[gid] = make_int4(0, 0, 0, 0);
    if (gid == 0) hist[NC * 4] = 0;               // tailcnt
}

// decode point, write packed float4 (w = orig idx), cell id, histogram (validated)
__global__ __launch_bounds__(256) void hist_kernel(const float* __restrict__ pred,
                                                   const float* __restrict__ target,
                                                   float4* __restrict__ pts,
                                                   int* __restrict__ cellids,
                                                   int* __restrict__ hist) {
    int t = blockIdx.x * 256 + threadIdx.x;      // 0..65535
    int cloud = t >> 15, w = t & 32767, b = w >> 14, i = w & 16383;
    const float* src = cloud ? target : pred;
    float x = src[(b * NPTS + i) * 3 + 0];
    float y = src[(b * NPTS + i) * 3 + 1];
    float z = src[(b * NPTS + i) * 3 + 2];
    int set = cloud * 2 + b;
    int c = (cellof(z) * G + cellof(y)) * G + cellof(x);
    int u = (set << 14) + i;
    pts[u] = make_float4(x, y, z, __int_as_float(i));
    cellids[u] = c;
    atomicAdd(&hist[(set << 15) + c], 1);
}

// per-set exclusive scan: wave shfl-scan + one cross-wave pass (2 barriers)
__global__ __launch_bounds__(1024) void scan_kernel(const int* __restrict__ hist,
                                                    int* __restrict__ cs,
                                                    int* __restrict__ next) {
    const int s = blockIdx.x;            // set 0..3
    const int tid = threadIdx.x;
    const int lane = tid & 63, wv = tid >> 6;
    int v[32]; int sum = 0;
    const int base = (s << 15) + tid * 32;
    #pragma unroll
    for (int r = 0; r < 32; ++r) { v[r] = hist[base + r]; sum += v[r]; }

    // inclusive wave scan of per-thread sums
    int ws = sum;
    #pragma unroll
    for (int off = 1; off < 64; off <<= 1) {
        int t = __shfl_up(ws, off);
        if (lane >= off) ws += t;
    }
    __shared__ int wtot[16], wbase[16];
    if (lane == 63) wtot[wv] = ws;
    __syncthreads();
    if (tid == 0) {
        int run = 0;
        #pragma unroll
        for (int i = 0; i < 16; ++i) { wbase[i] = run; run += wtot[i]; }
    }
    __syncthreads();

    int run = wbase[wv] + ws - sum;      // exclusive prefix for this thread
    const int cbase = s * (NC + 1) + tid * 32;
    #pragma unroll
    for (int r = 0; r < 32; ++r) {
        cs[cbase + r] = run;
        next[base + r] = run;
        run += v[r];
    }
    if (tid == 1023) cs[s * (NC + 1) + NC] = run;   // = 16384
}

__global__ __launch_bounds__(256) void scatter_kernel(const float4* __restrict__ pts,
                                                      const int* __restrict__ cellids,
                                                      int* __restrict__ next,
                                                      float4* __restrict__ sorted) {
    int u = blockIdx.x * 256 + threadIdx.x;      // 0..65535
    int set = u >> 14;
    int c = cellids[u];
    int idx = atomicAdd(&next[(set << 15) + c], 1);
    sorted[(set << 14) + idx] = pts[u];
}

#define EVAL(j) { float4 p = sr[j];                                   \
    float dx = q.x - p.x, dy = q.y - p.y, dz = q.z - p.z;             \
    md2 = fminf(md2, fmaf(dx, dx, fmaf(dy, dy, dz * dz))); }

// Bulk: 8 lanes/query. Stage 1 = nearest 2x2x2 cell box (4 CSR runs, g>=0.125).
// Stage 2 (per-quad predicated, wave-voted) = full 3x3x3 top-up (g>=0.25).
__global__ __launch_bounds__(256) void nnA_kernel(const float4* __restrict__ sorted,
                                                  const int* __restrict__ cs,
                                                  float* __restrict__ dout,
                                                  int* __restrict__ tailcnt,
                                                  int* __restrict__ taillist) {
    const int gthr = blockIdx.x * 256 + threadIdx.x;  // 0..524287
    const int u = gthr >> 3;                          // sorted-order query id
    const int l8 = gthr & 7;
    const int z = u >> 14;
    float4 q = sorted[u];
    const float4* __restrict__ sr = sorted + ((z ^ 2) << 14);
    const int* __restrict__ csr = cs + (z ^ 2) * (NC + 1);

    const int cx = cellof(q.x), cy = cellof(q.y), cz = cellof(q.z);
    // nearest 2-cell window per axis, clamped: all cells valid, no bounds checks
    int xlo = cx - ((q.x - (cx * CW - 4.0f)) < 0.125f); xlo = min(max(xlo, 0), G - 2);
    int ylo = cy - ((q.y - (cy * CW - 4.0f)) < 0.125f); ylo = min(max(ylo, 0), G - 2);
    int zlo = cz - ((q.z - (cz * CW - 4.0f)) < 0.125f); zlo = min(max(zlo, 0), G - 2);

    int s0a[4], s1a[4];
    #pragma unroll
    for (int r = 0; r < 4; ++r) {
        const int zz = zlo + (r >> 1), yy = ylo + (r & 1);
        const int rowbase = (zz * G + yy) * G;
        s0a[r] = csr[rowbase + xlo];
        s1a[r] = csr[rowbase + xlo + 2];
    }

    float md2 = __builtin_inff();
    #pragma unroll
    for (int r = 0; r < 4; ++r)
        for (int j = s0a[r] + l8; j < s1a[r]; j += 8) EVAL(j)

    md2 = fminf(md2, __shfl_xor(md2, 1));
    md2 = fminf(md2, __shfl_xor(md2, 2));
    md2 = fminf(md2, __shfl_xor(md2, 4));

    // stage-1 bound: faces of the 2x2x2 box (>= 0.125 or domain-edge inf)
    float g1 = __builtin_inff();
    if (xlo > 0)         g1 = fminf(g1, q.x - (xlo * CW - 4.0f));
    if (xlo + 1 < G - 1) g1 = fminf(g1, ((xlo + 2) * CW - 4.0f) - q.x);
    if (ylo > 0)         g1 = fminf(g1, q.y - (ylo * CW - 4.0f));
    if (ylo + 1 < G - 1) g1 = fminf(g1, ((ylo + 2) * CW - 4.0f) - q.y);
    if (zlo > 0)         g1 = fminf(g1, q.z - (zlo * CW - 4.0f));
    if (zlo + 1 < G - 1) g1 = fminf(g1, ((zlo + 2) * CW - 4.0f) - q.z);
    const bool ok1 = md2 <= g1 * g1;

    if (__any(!ok1)) {
        if (!ok1) {   // quad-uniform predicate; re-min over 3x3x3 superset (idempotent)
            const int x3 = max(cx - 1, 0), xh3 = min(cx + 1, G - 1);
            #pragma unroll
            for (int i = 0; i < 9; ++i) {
                const int zz = cz + i / 3 - 1, yy = cy + i % 3 - 1;
                if ((unsigned)zz >= G || (unsigned)yy >= G) continue;
                const int rowbase = (zz * G + yy) * G;
                const int s0 = csr[rowbase + x3], s1 = csr[rowbase + xh3 + 1];
                for (int j = s0 + l8; j < s1; j += 8) EVAL(j)
            }
        }
        md2 = fminf(md2, __shfl_xor(md2, 1));
        md2 = fminf(md2, __shfl_xor(md2, 2));
        md2 = fminf(md2, __shfl_xor(md2, 4));
    }

    if (l8 == 0) {
        // stage-2 bound: faces of the 3x3x3 box (>= 0.25 or inf); g2 >= g1
        float g2 = __builtin_inff();
        if (cx - 1 > 0)     g2 = fminf(g2, q.x - ((cx - 1) * CW - 4.0f));
        if (cx + 1 < G - 1) g2 = fminf(g2, ((cx + 2) * CW - 4.0f) - q.x);
        if (cy - 1 > 0)     g2 = fminf(g2, q.y - ((cy - 1) * CW - 4.0f));
        if (cy + 1 < G - 1) g2 = fminf(g2, ((cy + 2) * CW - 4.0f) - q.y);
        if (cz - 1 > 0)     g2 = fminf(g2, q.z - ((cz - 1) * CW - 4.0f));
        if (cz + 1 < G - 1) g2 = fminf(g2, ((cz + 2) * CW - 4.0f) - q.z);
        const int oi = __float_as_int(q.w);
        if (md2 <= g2 * g2) {
            dout[(z << 14) + oi] = sqrtf(md2);
        } else {
            int idx = atomicAdd(tailcnt, 1);
            taillist[idx] = u;        // dout written by tail kernel
        }
    }
}

// Tail: ONE WAVE per query, lane-parallel shell runs (validated r18/r19)
__global__ __launch_bounds__(256) void tail_kernel(const float4* __restrict__ sorted,
                                                   const int* __restrict__ cs,
                                                   const int* __restrict__ tailcnt,
                                                   const int* __restrict__ taillist,
                                                   float* __restrict__ dout) {
    const int cnt = *tailcnt;
    const int wid = blockIdx.x * 4 + (threadIdx.x >> 6);
    const int ln = threadIdx.x & 63;
    const int nw = gridDim.x * 4;

    for (int t = wid; t < cnt; t += nw) {
        const int u = taillist[t];
        const int z = u >> 14;
        float4 q = sorted[u];
        const float4* __restrict__ sr = sorted + ((z ^ 2) << 14);
        const int* __restrict__ csr = cs + (z ^ 2) * (NC + 1);
        const int cx = cellof(q.x), cy = cellof(q.y), cz = cellof(q.z);

        float md2 = __builtin_inff();

        {
            const int rowbase = (cz * G + cy) * G;
            const int s0 = csr[rowbase + cx], s1 = csr[rowbase + cx + 1];
            for (int j = s0 + ln; j < s1; j += 64) EVAL(j)
        }

        for (int k = 1; k < G; ++k) {
            #pragma unroll
            for (int off = 1; off < 64; off <<= 1)
                md2 = fminf(md2, __shfl_xor(md2, off));
            const int km = k - 1;
            float g = __builtin_inff();
            if (cx - km > 0)     g = fminf(g, q.x - ((cx - km) * CW - 4.0f));
            if (cx + km < G - 1) g = fminf(g, ((cx + km + 1) * CW - 4.0f) - q.x);
            if (cy - km > 0)     g = fminf(g, q.y - ((cy - km) * CW - 4.0f));
            if (cy + km < G - 1) g = fminf(g, ((cy + km + 1) * CW - 4.0f) - q.y);
            if (cz - km > 0)     g = fminf(g, q.z - ((cz - km) * CW - 4.0f));
            if (cz + km < G - 1) g = fminf(g, ((cz + km + 1) * CW - 4.0f) - q.z);
            if (md2 <= g * g) break;

            const int W = 2 * k + 1, Wm = 2 * k - 1;
            const int A = 2 * W, Bc = 2 * Wm;
            const int R = A + Bc + 2 * Wm * Wm;
            for (int m = ln; m < R; m += 64) {
                int zz, yy, xlo, xhi;
                if (m < A) {
                    zz = cz + ((m < W) ? -k : k);
                    yy = cy + ((m < W) ? m : m - W) - k;
                    if ((unsigned)zz >= G || (unsigned)yy >= G) continue;
                    xlo = max(cx - k, 0); xhi = min(cx + k, G - 1);
                } else if (m < A + Bc) {
                    const int t2 = m - A;
                    zz = cz + ((t2 < Wm) ? t2 : t2 - Wm) - (k - 1);
                    yy = cy + ((t2 < Wm) ? -k : k);
                    if ((unsigned)zz >= G || (unsigned)yy >= G) continue;
                    xlo = max(cx - k, 0); xhi = min(cx + k, G - 1);
                } else {
                    int t2 = m - A - Bc;
                    const int side = t2 & 1; t2 >>= 1;
                    zz = cz + t2 / Wm - (k - 1);
                    yy = cy + t2 % Wm - (k - 1);
                    const int xx = cx + (side ? k : -k);
                    if ((unsigned)zz >= G || (unsigned)yy >= G || (unsigned)xx >= G) continue;
                    xlo = xx; xhi = xx;
                }
                const int rowbase = (zz * G + yy) * G;
                const int s0 = csr[rowbase + xlo], s1 = csr[rowbase + xhi + 1];
                for (int j = s0; j < s1; ++j) EVAL(j)
            }
        }

        #pragma unroll
        for (int off = 1; off < 64; off <<= 1)
            md2 = fminf(md2, __shfl_xor(md2, off));
        if (ln == 0) {
            const int oi = __float_as_int(q.w);
            dout[(z << 14) + oi] = sqrtf(md2);
        }
    }
}
#undef EVAL

// single-block final reduce: fixed order -> deterministic (validated r16)
__global__ __launch_bounds__(1024) void reduce_kernel(const float* __restrict__ dout,
                                                      float* __restrict__ out) {
    float s = 0.f;
    #pragma unroll
    for (int k = 0; k < 64; ++k)
        s += dout[k * 1024 + threadIdx.x];
    #pragma unroll
    for (int off = 32; off; off >>= 1) s += __shfl_down(s, off);
    __shared__ float wsum[16];
    int lane = threadIdx.x & 63, wv = threadIdx.x >> 6;
    if (lane == 0) wsum[wv] = s;
    __syncthreads();
    if (threadIdx.x == 0) {
        float tt = 0.f;
        #pragma unroll
        for (int i = 0; i < 16; ++i) tt += wsum[i];
        out[0] = tt / (float)TOTQ;
    }
}

extern "C" void kernel_launch(void* const* d_in, const int* in_sizes, int n_in,
                              void* d_out, int out_size, void* d_ws, size_t ws_size,
                              hipStream_t stream) {
    const float* pred   = (const float*)d_in[0];
    const float* target = (const float*)d_in[1];
    char* ws = (char*)d_ws;

    float4* pts      = (float4*)(ws);                                   // 1 MiB
    float4* sorted   = (float4*)(ws + (size_t)1024 * 1024);             // 1 MiB
    int*    cellids  = (int*)  (ws + (size_t)2048 * 1024);              // 256 KiB
    int*    hist     = (int*)  (ws + (size_t)2304 * 1024);              // 512 KiB (+tailcnt)
    int*    next     = (int*)  (ws + (size_t)2848 * 1024);              // 512 KiB
    int*    cs       = (int*)  (ws + (size_t)3360 * 1024);              // ~513 KiB
    int*    taillist = (int*)  (ws + (size_t)3904 * 1024);              // 256 KiB
    float*  dout     = (float*)(ws + (size_t)4160 * 1024);              // 256 KiB
    int*    tailcnt  = hist + NC * 4;                                   // after hist
    float*  out      = (float*)d_out;

    zero_kernel<<<128, 256, 0, stream>>>(hist);

    hist_kernel<<<TOTP / 256, 256, 0, stream>>>(pred, target, pts, cellids, hist);
    scan_kernel<<<4, 1024, 0, stream>>>(hist, cs, next);
    scatter_kernel<<<TOTP / 256, 256, 0, stream>>>(pts, cellids, next, sorted);

    nnA_kernel<<<TOTP * 8 / 256, 256, 0, stream>>>(sorted, cs, dout, tailcnt, taillist);
    tail_kernel<<<512, 256, 0, stream>>>(sorted, cs, tailcnt, taillist, dout);

    reduce_kernel<<<1, 1024, 0, stream>>>(dout, out);
}